// Round 2
// baseline (578.602 us; speedup 1.0000x reference)
//
#include <hip/hip_runtime.h>
#include <math.h>

#define DIMC 64
#define KK 4
#define BATCH 16
#define HH 256
#define WW 256
#define HO 127
#define WO 127
#define PIX (HO*WO)                  // 16129
#define OUT_MAIN (BATCH*DIMC*PIX)    // 16516096

typedef __bf16 bf16x4 __attribute__((ext_vector_type(4)));
typedef __bf16 bf16x8 __attribute__((ext_vector_type(8)));
typedef float floatx16 __attribute__((ext_vector_type(16)));

// ---------- BIG-WS layout (float offsets) ----------
// a2: 1,638,400 bf16 = 819,200 floats
// xb: 16*4*256*256*16 = 67,108,864 bf16 = 33,554,432 floats
#define BG_A2F    0
#define BG_XB     819200
#define BG_POOLED (BG_XB + 33554432)          // 34,373,632
#define BG_ATT    (BG_POOLED + 1024)
#define BG_AGGB   (BG_ATT + 64)
#define BG_END    (BG_AGGB + 1024)            // 34,375,744 floats
#define BG_NEED_BYTES ((size_t)BG_END * 4)    // ~137.5 MB

// ---------- SMALL-WS (fallback, R2) layout ----------
#define SM_A2F    0
#define SM_POOLED 819200
#define SM_ATT    (SM_POOLED + 1024)
#define SM_AGGB   (SM_ATT + 64)

#define IXN 68
#define CIP 20

// rows per pool block (R1: amortize the 96-shfl reduction tree over 8 rows)
#define PROWS 8

// ================= shared kernels =================

// attention + agg_b (pooled holds raw sums; /65536 here)
__global__ void att_kernel(const float* __restrict__ fc1_w, const float* __restrict__ fc1_b,
                           const float* __restrict__ fc2_w, const float* __restrict__ fc2_b,
                           const float* __restrict__ bias,
                           const float* __restrict__ pooled_raw,
                           float* __restrict__ att_out, float* __restrict__ aggb_out) {
    __shared__ float satt[BATCH*KK];
    int tid = threadIdx.x;
    if (tid < BATCH) {
        int b = tid;
        const float* pooled = pooled_raw + b*DIMC;
        float a[KK];
        #pragma unroll
        for (int j = 0; j < KK; ++j) {
            float s = fc1_b[j];
            for (int i = 0; i < DIMC; ++i) s += pooled[i] * (1.f/65536.f) * fc1_w[j*DIMC + i];
            a[j] = fmaxf(s, 0.f);
        }
        float l[KK]; float m = -1e30f;
        #pragma unroll
        for (int j = 0; j < KK; ++j) {
            float s = fc2_b[j];
            #pragma unroll
            for (int k = 0; k < KK; ++k) s += a[k] * fc2_w[j*KK + k];
            l[j] = s; m = fmaxf(m, s);
        }
        float e[KK]; float Z = 0.f;
        #pragma unroll
        for (int j = 0; j < KK; ++j) { e[j] = expf(l[j] - m); Z += e[j]; }
        float invZ = 1.f / Z;
        #pragma unroll
        for (int j = 0; j < KK; ++j) {
            float av = e[j] * invZ;
            satt[b*KK + j] = av;
            att_out[b*KK + j] = av;
        }
    }
    __syncthreads();
    for (int idx = tid; idx < BATCH*DIMC; idx += blockDim.x) {
        int b = idx / DIMC, o = idx % DIMC;
        float s = 0.f;
        #pragma unroll
        for (int k = 0; k < KK; ++k) s += satt[b*KK + k] * bias[k*DIMC + o];
        aggb_out[idx] = s;
    }
}

// mix weight bank -> w_ret (fp32) + a2 (bf16 MFMA-A layout)
__global__ void agg_kernel(const float* __restrict__ weight, const float* __restrict__ att,
                           __bf16* __restrict__ a2, float* __restrict__ wret) {
    int v = blockIdx.x * 256 + threadIdx.x;   // 0..1638399
    int i = v & 63;                            // ci
    int t = (v >> 6) % 25;                     // tap
    int o = (v / 1600) & 63;                   // cout
    int b = v / 102400;
    float s = 0.f;
    #pragma unroll
    for (int k = 0; k < KK; ++k)
        s += att[b*KK + k] * weight[((k*DIMC + o)*DIMC + i)*25 + t];
    wret[v] = s;
    a2[(((b*4 + (i >> 4))*25 + t)*64 + o)*16 + (i & 15)] = (__bf16)s;
}

// ================= BIG-WS fast path =================

// fused pool + fp32->bf16 swizzle: xb layout [b][chunk][y][x][ci16]
// R1: one block covers PROWS rows; per-channel sums accumulate in registers
// across rows so the 16x6 shfl tree runs ONCE per block (was once per row).
__global__ __launch_bounds__(256) void pool_cvt_kernel(const float* __restrict__ x,
                                                       __bf16* __restrict__ xb,
                                                       float* __restrict__ pooled) {
    int yg = blockIdx.x, ch = blockIdx.y, b = blockIdx.z;
    int tid = threadIdx.x;
    float acc[16];
    #pragma unroll
    for (int s = 0; s < 16; ++s) acc[s] = 0.f;
    const float* srcbase = x + (((size_t)(b*DIMC + ch*16))*HH + yg*PROWS)*WW + tid;
    __bf16* dstbase = xb + ((((size_t)(b*4 + ch))*HH + yg*PROWS)*WW + tid)*16;
    for (int ry = 0; ry < PROWS; ++ry) {
        const float* src = srcbase + (size_t)ry*WW;
        float v[16];
        #pragma unroll
        for (int s = 0; s < 16; ++s) v[s] = src[(size_t)s*HH*WW];
        bf16x8 lo, hi;
        #pragma unroll
        for (int j = 0; j < 8; ++j) { lo[j] = (__bf16)v[j]; hi[j] = (__bf16)v[j+8]; }
        __bf16* dst = dstbase + (size_t)ry*WW*16;
        *(bf16x8*)dst = lo;          // byte addr multiple of 32 - aligned
        *(bf16x8*)(dst + 8) = hi;
        #pragma unroll
        for (int s = 0; s < 16; ++s) acc[s] += v[s];
    }
    #pragma unroll
    for (int s = 0; s < 16; ++s) {
        float t = acc[s];
        for (int off = 32; off > 0; off >>= 1) t += __shfl_down(t, off, 64);
        acc[s] = t;
    }
    __shared__ float part[4][16];
    int lane = tid & 63, w = tid >> 6;
    if (lane == 0) {
        #pragma unroll
        for (int s = 0; s < 16; ++s) part[w][s] = acc[s];
    }
    __syncthreads();
    if (tid < 16) {
        float p = part[0][tid] + part[1][tid] + part[2][tid] + part[3][tid];
        atomicAdd(&pooled[b*DIMC + ch*16 + tid], p);
    }
}

// MFMA conv, staging from pre-converted bf16 xb.
// block: 128 thr = 2 waves; tile = 4 out rows x 32 cols x 64 couts.
// wave rp handles rows {2rp,2rp+1}, BOTH cout halves (B-frag reused 2x).
__global__ __launch_bounds__(128) void conv_big_kernel(const __bf16* __restrict__ xb,
                                                       const __bf16* __restrict__ a2,
                                                       const float* __restrict__ aggb,
                                                       float* __restrict__ out) {
    __shared__ __bf16 lin[11*IXN*CIP];   // 29,920 B
    int ct = blockIdx.x;      // col tile 0..3
    int rg = blockIdx.y;      // row group 0..31
    int b  = blockIdx.z;
    int tid = threadIdx.x, lane = tid & 63, rp = tid >> 6;
    int n = lane & 31, h = lane >> 5;
    int gx0 = ct*64 - 1, gy0 = rg*8 - 1;
    int bconst = 40*n + 8*h;
    floatx16 acc00 = {}, acc01 = {}, acc10 = {}, acc11 = {};

    for (int c = 0; c < 4; ++c) {
        __syncthreads();
        const __bf16* xsrc = xb + ((size_t)(b*4 + c))*HH*WW*16;
        // 11 rows x 67 cols x 16ci in 16-B pieces: 1474 pieces
        #pragma unroll
        for (int it = 0; it < 12; ++it) {
            int idx = it*128 + tid;
            if (idx < 1474) {
                int r = idx / 134;
                int q = idx - r*134;
                int ix = q >> 1, hh = q & 1;
                int gy = gy0 + r, gx = gx0 + ix;
                bf16x8 vv = {};
                if ((unsigned)gy < (unsigned)HH && (unsigned)gx < (unsigned)WW)
                    vv = *(const bf16x8*)(xsrc + ((size_t)gy*WW + gx)*16 + hh*8);
                // two 8-B LDS stores: byte addr = r*2720 + ix*40 + hh*16 (+8), 8-aligned
                __bf16* dp = lin + (r*IXN + ix)*CIP + hh*8;
                bf16x4 vlo = {vv[0], vv[1], vv[2], vv[3]};
                bf16x4 vhi = {vv[4], vv[5], vv[6], vv[7]};
                *(bf16x4*)dp = vlo;
                *(bf16x4*)(dp + 4) = vhi;
            }
        }
        __syncthreads();

        const __bf16* ap = a2 + ((size_t)(b*4 + c)*25*64 + n)*16 + h*8;
        #pragma unroll 5
        for (int t = 0; t < 25; ++t) {
            int dy = t / 5, dx = t - dy*5;
            bf16x8 a0 = *(const bf16x8*)(ap + t*1024);        // couts 0..31
            bf16x8 a1 = *(const bf16x8*)(ap + t*1024 + 512);  // couts 32..63
            {
                int iy = 4*rp + dy;
                const __bf16* bp = lin + (iy*IXN + dx)*CIP + bconst;
                bf16x4 l0 = *(const bf16x4*)bp;
                bf16x4 h0 = *(const bf16x4*)(bp + 4);
                bf16x8 bb = __builtin_shufflevector(l0, h0, 0,1,2,3,4,5,6,7);
                acc00 = __builtin_amdgcn_mfma_f32_32x32x16_bf16(a0, bb, acc00, 0, 0, 0);
                acc01 = __builtin_amdgcn_mfma_f32_32x32x16_bf16(a1, bb, acc01, 0, 0, 0);
            }
            {
                int iy = 4*rp + 2 + dy;
                const __bf16* bp = lin + (iy*IXN + dx)*CIP + bconst;
                bf16x4 l0 = *(const bf16x4*)bp;
                bf16x4 h0 = *(const bf16x4*)(bp + 4);
                bf16x8 bb = __builtin_shufflevector(l0, h0, 0,1,2,3,4,5,6,7);
                acc10 = __builtin_amdgcn_mfma_f32_32x32x16_bf16(a0, bb, acc10, 0, 0, 0);
                acc11 = __builtin_amdgcn_mfma_f32_32x32x16_bf16(a1, bb, acc11, 0, 0, 0);
            }
        }
    }

    int oxg = ct*32 + n;
    if (oxg < WO) {
        #pragma unroll
        for (int nt = 0; nt < 2; ++nt) {
            int oy = rg*4 + 2*rp + nt;
            if (oy >= HO) continue;
            #pragma unroll
            for (int mh = 0; mh < 2; ++mh) {
                const floatx16& acc = nt ? (mh ? acc11 : acc10) : (mh ? acc01 : acc00);
                #pragma unroll
                for (int reg = 0; reg < 16; ++reg) {
                    int cout = mh*32 + (reg & 3) + 8*(reg >> 2) + 4*h;
                    float val = acc[reg] + aggb[b*DIMC + cout];
                    out[(size_t)(b*DIMC + cout)*PIX + oy*WO + oxg] = val;
                }
            }
        }
    }
}

// ================= SMALL-WS fallback (R2 pipeline) =================

__global__ void pool_kernel(const float* __restrict__ x, float* __restrict__ pooled) {
    int plane = blockIdx.x >> 1, half = blockIdx.x & 1;
    const float4* p = (const float4*)(x + (size_t)plane * (HH*WW)) + half * 8192;
    float s = 0.f;
    for (int k = threadIdx.x; k < 8192; k += 256) {
        float4 v = p[k];
        s += (v.x + v.y) + (v.z + v.w);
    }
    for (int off = 32; off > 0; off >>= 1) s += __shfl_down(s, off, 64);
    __shared__ float red[4];
    if ((threadIdx.x & 63) == 0) red[threadIdx.x >> 6] = s;
    __syncthreads();
    if (threadIdx.x == 0) atomicAdd(&pooled[plane], red[0] + red[1] + red[2] + red[3]);
}

// conv staging directly from fp32 x (R2, known-good)
__global__ __launch_bounds__(256) void conv_small_kernel(const float* __restrict__ x,
                                                         const __bf16* __restrict__ a2,
                                                         const float* __restrict__ aggb,
                                                         float* __restrict__ out) {
    __shared__ __bf16 lin[11*IXN*CIP];
    int ct = blockIdx.x;
    int rg = blockIdx.y;
    int b  = blockIdx.z;
    int tid = threadIdx.x, lane = tid & 63, w = tid >> 6;
    int mh = w & 1;
    int rp = w >> 1;
    int n = lane & 31, h = lane >> 5;
    floatx16 acc0 = {}, acc1 = {};
    int gx0 = ct*64 - 1;
    int gy0 = rg*8 - 1;
    const float* xbse = x + (size_t)b * (DIMC*HH*WW);
    int bconst = 40*n + 8*h;

    for (int c = 0; c < 4; ++c) {
        __syncthreads();
        for (int rr = w; rr < 176; rr += 4) {
            int s = rr / 11, iy = rr - s*11;
            int gy = gy0 + iy;
            bool rowok = (unsigned)gy < (unsigned)HH;
            const float* row = xbse + (size_t)(c*16 + s)*(HH*WW) + gy*WW;
            int gx = gx0 + lane;
            float v0 = 0.f;
            if (rowok && (unsigned)gx < (unsigned)WW) v0 = row[gx];
            lin[(iy*IXN + lane)*CIP + s] = (__bf16)v0;
            int ix2 = lane + 64;
            if (ix2 < 67) {
                int gx2 = gx0 + ix2;
                float v1 = 0.f;
                if (rowok && (unsigned)gx2 < (unsigned)WW) v1 = row[gx2];
                lin[(iy*IXN + ix2)*CIP + s] = (__bf16)v1;
            }
        }
        __syncthreads();

        const __bf16* ap = a2 + ((size_t)(b*4 + c)*25*64 + (size_t)(mh*32 + n))*16 + h*8;
        #pragma unroll 5
        for (int t = 0; t < 25; ++t) {
            int dy = t / 5, dx = t - dy*5;
            bf16x8 a = *(const bf16x8*)(ap + t*1024);
            {
                int iy = 4*rp + dy;
                const __bf16* bp = lin + (iy*IXN + dx)*CIP + bconst;
                bf16x4 lo = *(const bf16x4*)bp;
                bf16x4 hi = *(const bf16x4*)(bp + 4);
                bf16x8 bb = __builtin_shufflevector(lo, hi, 0,1,2,3,4,5,6,7);
                acc0 = __builtin_amdgcn_mfma_f32_32x32x16_bf16(a, bb, acc0, 0, 0, 0);
            }
            {
                int iy = 4*rp + 2 + dy;
                const __bf16* bp = lin + (iy*IXN + dx)*CIP + bconst;
                bf16x4 lo = *(const bf16x4*)bp;
                bf16x4 hi = *(const bf16x4*)(bp + 4);
                bf16x8 bb = __builtin_shufflevector(lo, hi, 0,1,2,3,4,5,6,7);
                acc1 = __builtin_amdgcn_mfma_f32_32x32x16_bf16(a, bb, acc1, 0, 0, 0);
            }
        }
    }

    int oxg = ct*32 + n;
    if (oxg < WO) {
        #pragma unroll
        for (int nt = 0; nt < 2; ++nt) {
            int oy = rg*4 + 2*rp + nt;
            if (oy >= HO) continue;
            const floatx16& acc = nt ? acc1 : acc0;
            #pragma unroll
            for (int reg = 0; reg < 16; ++reg) {
                int row = (reg & 3) + 8*(reg >> 2) + 4*h;
                int cout = mh*32 + row;
                float val = acc[reg] + aggb[b*DIMC + cout];
                out[(size_t)(b*DIMC + cout)*PIX + oy*WO + oxg] = val;
            }
        }
    }
}

extern "C" void kernel_launch(void* const* d_in, const int* in_sizes, int n_in,
                              void* d_out, int out_size, void* d_ws, size_t ws_size,
                              hipStream_t stream) {
    const float* x      = (const float*)d_in[0];
    const float* fc1_w  = (const float*)d_in[1];
    const float* fc1_b  = (const float*)d_in[2];
    const float* fc2_w  = (const float*)d_in[3];
    const float* fc2_b  = (const float*)d_in[4];
    const float* weight = (const float*)d_in[5];
    const float* bias   = (const float*)d_in[6];
    float* out = (float*)d_out;
    float* ws  = (float*)d_ws;

    if (ws_size >= BG_NEED_BYTES) {
        __bf16* a2 = (__bf16*)(ws + BG_A2F);
        __bf16* xb = (__bf16*)(ws + BG_XB);
        hipMemsetAsync(ws + BG_POOLED, 0, 1024*sizeof(float), stream);
        pool_cvt_kernel<<<dim3(HH/PROWS, 4, BATCH), 256, 0, stream>>>(x, xb, ws + BG_POOLED);
        att_kernel<<<1, 256, 0, stream>>>(fc1_w, fc1_b, fc2_w, fc2_b, bias,
                                          ws + BG_POOLED, ws + BG_ATT, ws + BG_AGGB);
        agg_kernel<<<BATCH*DIMC*DIMC*25/256, 256, 0, stream>>>(weight, ws + BG_ATT,
                                                               a2, out + OUT_MAIN);
        conv_big_kernel<<<dim3(4, 32, BATCH), 128, 0, stream>>>(xb, a2, ws + BG_AGGB, out);
    } else {
        __bf16* a2 = (__bf16*)(ws + SM_A2F);
        hipMemsetAsync(ws + SM_POOLED, 0, 1024*sizeof(float), stream);
        pool_kernel<<<2*BATCH*DIMC, 256, 0, stream>>>(x, ws + SM_POOLED);
        att_kernel<<<1, 256, 0, stream>>>(fc1_w, fc1_b, fc2_w, fc2_b, bias,
                                          ws + SM_POOLED, ws + SM_ATT, ws + SM_AGGB);
        agg_kernel<<<BATCH*DIMC*DIMC*25/256, 256, 0, stream>>>(weight, ws + SM_ATT,
                                                               a2, out + OUT_MAIN);
        conv_small_kernel<<<dim3(4, 32, BATCH), 256, 0, stream>>>(x, a2, ws + SM_AGGB, out);
    }
}

// Round 3
// 564.224 us; speedup vs baseline: 1.0255x; 1.0255x over previous
//
#include <hip/hip_runtime.h>
#include <math.h>

#define DIMC 64
#define KK 4
#define BATCH 16
#define HH 256
#define WW 256
#define HO 127
#define WO 127
#define PIX (HO*WO)                  // 16129
#define OUT_MAIN (BATCH*DIMC*PIX)    // 16516096

typedef __bf16 bf16x4 __attribute__((ext_vector_type(4)));
typedef __bf16 bf16x8 __attribute__((ext_vector_type(8)));
typedef float floatx4 __attribute__((ext_vector_type(4)));
typedef float floatx16 __attribute__((ext_vector_type(16)));

// ---------- BIG-WS layout (float offsets) ----------
#define BG_A2F    0
#define BG_XB     819200
#define BG_POOLED (BG_XB + 33554432)          // 34,373,632
#define BG_ATT    (BG_POOLED + 1024)
#define BG_AGGB   (BG_ATT + 64)
#define BG_END    (BG_AGGB + 1024)            // 34,375,744 floats
#define BG_NEED_BYTES ((size_t)BG_END * 4)    // ~137.5 MB

// ---------- SMALL-WS (fallback, R2) layout ----------
#define SM_A2F    0
#define SM_POOLED 819200
#define SM_ATT    (SM_POOLED + 1024)
#define SM_AGGB   (SM_ATT + 64)

#define IXN 68
#define CIP 20

// rows per pool block
#define PROWS 8

// ================= shared kernels =================

// attention + agg_b (pooled holds raw sums; /65536 here)
// R2: fc1 parallelized across all 256 threads (b,j,quarter) + 4-lane tree reduce.
__global__ void att_kernel(const float* __restrict__ fc1_w, const float* __restrict__ fc1_b,
                           const float* __restrict__ fc2_w, const float* __restrict__ fc2_b,
                           const float* __restrict__ bias,
                           const float* __restrict__ pooled_raw,
                           float* __restrict__ att_out, float* __restrict__ aggb_out) {
    __shared__ float sa[BATCH][KK];
    __shared__ float satt[BATCH*KK];
    int tid = threadIdx.x;
    {
        int b = tid >> 4, j = (tid >> 2) & 3, q = tid & 3;
        const float* pooled = pooled_raw + b*DIMC + q*16;
        const float* wrow   = fc1_w + j*DIMC + q*16;
        float s = 0.f;
        #pragma unroll
        for (int i = 0; i < 16; ++i) s += pooled[i] * (1.f/65536.f) * wrow[i];
        s += __shfl_xor(s, 1, 64);
        s += __shfl_xor(s, 2, 64);
        if (q == 0) sa[b][j] = fmaxf(s + fc1_b[j], 0.f);
    }
    __syncthreads();
    if (tid < BATCH) {
        int b = tid;
        float l[KK]; float m = -1e30f;
        #pragma unroll
        for (int j = 0; j < KK; ++j) {
            float s = fc2_b[j];
            #pragma unroll
            for (int k = 0; k < KK; ++k) s += sa[b][k] * fc2_w[j*KK + k];
            l[j] = s; m = fmaxf(m, s);
        }
        float e[KK]; float Z = 0.f;
        #pragma unroll
        for (int j = 0; j < KK; ++j) { e[j] = expf(l[j] - m); Z += e[j]; }
        float invZ = 1.f / Z;
        #pragma unroll
        for (int j = 0; j < KK; ++j) {
            float av = e[j] * invZ;
            satt[b*KK + j] = av;
            att_out[b*KK + j] = av;
        }
    }
    __syncthreads();
    for (int idx = tid; idx < BATCH*DIMC; idx += blockDim.x) {
        int b = idx / DIMC, o = idx % DIMC;
        float s = 0.f;
        #pragma unroll
        for (int k = 0; k < KK; ++k) s += satt[b*KK + k] * bias[k*DIMC + o];
        aggb_out[idx] = s;
    }
}

// mix weight bank -> w_ret (fp32) + a2 (bf16 MFMA-A layout)
__global__ void agg_kernel(const float* __restrict__ weight, const float* __restrict__ att,
                           __bf16* __restrict__ a2, float* __restrict__ wret) {
    int v = blockIdx.x * 256 + threadIdx.x;   // 0..1638399
    int i = v & 63;                            // ci
    int t = (v >> 6) % 25;                     // tap
    int o = (v / 1600) & 63;                   // cout
    int b = v / 102400;
    float s = 0.f;
    #pragma unroll
    for (int k = 0; k < KK; ++k)
        s += att[b*KK + k] * weight[((k*DIMC + o)*DIMC + i)*25 + t];
    wret[v] = s;
    a2[(((b*4 + (i >> 4))*25 + t)*64 + o)*16 + (i & 15)] = (__bf16)s;
}

// ================= BIG-WS fast path =================

// fused pool + fp32->bf16 swizzle: xb layout [b][chunk][y][x][ci16]
// R2: float4 loads (16B/lane), 4 px/thread; 4 waves x 2 rows = 8 rows/block.
__global__ __launch_bounds__(256) void pool_cvt_kernel(const float* __restrict__ x,
                                                       __bf16* __restrict__ xb,
                                                       float* __restrict__ pooled) {
    int yg = blockIdx.x, ch = blockIdx.y, b = blockIdx.z;
    int tid = threadIdx.x, lane = tid & 63, w = tid >> 6;
    float acc[16];
    #pragma unroll
    for (int s = 0; s < 16; ++s) acc[s] = 0.f;
    #pragma unroll
    for (int ry = 0; ry < 2; ++ry) {
        int y = yg*PROWS + w*2 + ry;
        const float* src = x + (((size_t)(b*DIMC + ch*16))*HH + y)*WW + lane*4;
        floatx4 v[16];
        #pragma unroll
        for (int s = 0; s < 16; ++s) v[s] = *(const floatx4*)(src + (size_t)s*HH*WW);
        __bf16* dst = xb + ((((size_t)(b*4 + ch))*HH + y)*WW + lane*4)*16;
        #pragma unroll
        for (int p = 0; p < 4; ++p) {
            bf16x8 lo, hi;
            #pragma unroll
            for (int j = 0; j < 8; ++j) {
                lo[j] = (__bf16)v[j][p];
                hi[j] = (__bf16)v[j+8][p];
            }
            *(bf16x8*)(dst + p*16) = lo;
            *(bf16x8*)(dst + p*16 + 8) = hi;
        }
        #pragma unroll
        for (int s = 0; s < 16; ++s)
            acc[s] += (v[s][0] + v[s][1]) + (v[s][2] + v[s][3]);
    }
    #pragma unroll
    for (int s = 0; s < 16; ++s) {
        float t = acc[s];
        for (int off = 32; off > 0; off >>= 1) t += __shfl_down(t, off, 64);
        acc[s] = t;
    }
    __shared__ float part[4][16];
    if (lane == 0) {
        #pragma unroll
        for (int s = 0; s < 16; ++s) part[w][s] = acc[s];
    }
    __syncthreads();
    if (tid < 16) {
        float p = part[0][tid] + part[1][tid] + part[2][tid] + part[3][tid];
        atomicAdd(&pooled[b*DIMC + ch*16 + tid], p);
    }
}

// MFMA conv, staging from pre-converted bf16 xb.
// R2 (T14): next chunk's 12x16B staging pieces prefetched into registers
// BEFORE the 25-tap MFMA loop; consumed (ds_write) after the next barrier.
// Load latency hides under ~1600cy of MFMA instead of sitting between barriers.
__global__ __launch_bounds__(128) void conv_big_kernel(const __bf16* __restrict__ xb,
                                                       const __bf16* __restrict__ a2,
                                                       const float* __restrict__ aggb,
                                                       float* __restrict__ out) {
    __shared__ __bf16 lin[11*IXN*CIP];   // 29,920 B
    int ct = blockIdx.x;      // col tile 0..3
    int rg = blockIdx.y;      // row group 0..31
    int b  = blockIdx.z;
    int tid = threadIdx.x, lane = tid & 63, rp = tid >> 6;
    int n = lane & 31, h = lane >> 5;
    int gx0 = ct*64 - 1, gy0 = rg*8 - 1;
    int bconst = 40*n + 8*h;
    floatx16 acc00 = {}, acc01 = {}, acc10 = {}, acc11 = {};

    bf16x8 pre[12];
    // prologue: issue chunk-0 staging loads
    {
        const __bf16* xsrc = xb + ((size_t)(b*4 + 0))*HH*WW*16;
        #pragma unroll
        for (int it = 0; it < 12; ++it) {
            int idx = it*128 + tid;
            bf16x8 vv = {};
            if (idx < 1474) {
                int r = idx / 134;
                int q = idx - r*134;
                int ix = q >> 1, hh = q & 1;
                int gy = gy0 + r, gx = gx0 + ix;
                if ((unsigned)gy < (unsigned)HH && (unsigned)gx < (unsigned)WW)
                    vv = *(const bf16x8*)(xsrc + ((size_t)gy*WW + gx)*16 + hh*8);
            }
            pre[it] = vv;
        }
    }

    for (int c = 0; c < 4; ++c) {
        __syncthreads();                 // previous chunk's readers done
        // write prefetched pieces -> LDS
        #pragma unroll
        for (int it = 0; it < 12; ++it) {
            int idx = it*128 + tid;
            if (idx < 1474) {
                int r = idx / 134;
                int q = idx - r*134;
                int ix = q >> 1, hh = q & 1;
                __bf16* dp = lin + (r*IXN + ix)*CIP + hh*8;
                bf16x4 vlo = {pre[it][0], pre[it][1], pre[it][2], pre[it][3]};
                bf16x4 vhi = {pre[it][4], pre[it][5], pre[it][6], pre[it][7]};
                *(bf16x4*)dp = vlo;
                *(bf16x4*)(dp + 4) = vhi;
            }
        }
        __syncthreads();
        // issue next chunk's loads now; consumed after the MFMA loop
        if (c < 3) {
            const __bf16* xsrc = xb + ((size_t)(b*4 + c + 1))*HH*WW*16;
            #pragma unroll
            for (int it = 0; it < 12; ++it) {
                int idx = it*128 + tid;
                bf16x8 vv = {};
                if (idx < 1474) {
                    int r = idx / 134;
                    int q = idx - r*134;
                    int ix = q >> 1, hh = q & 1;
                    int gy = gy0 + r, gx = gx0 + ix;
                    if ((unsigned)gy < (unsigned)HH && (unsigned)gx < (unsigned)WW)
                        vv = *(const bf16x8*)(xsrc + ((size_t)gy*WW + gx)*16 + hh*8);
                }
                pre[it] = vv;
            }
        }

        const __bf16* ap = a2 + ((size_t)(b*4 + c)*25*64 + n)*16 + h*8;
        #pragma unroll 5
        for (int t = 0; t < 25; ++t) {
            int dy = t / 5, dx = t - dy*5;
            bf16x8 a0 = *(const bf16x8*)(ap + t*1024);        // couts 0..31
            bf16x8 a1 = *(const bf16x8*)(ap + t*1024 + 512);  // couts 32..63
            {
                int iy = 4*rp + dy;
                const __bf16* bp = lin + (iy*IXN + dx)*CIP + bconst;
                bf16x4 l0 = *(const bf16x4*)bp;
                bf16x4 h0 = *(const bf16x4*)(bp + 4);
                bf16x8 bb = __builtin_shufflevector(l0, h0, 0,1,2,3,4,5,6,7);
                acc00 = __builtin_amdgcn_mfma_f32_32x32x16_bf16(a0, bb, acc00, 0, 0, 0);
                acc01 = __builtin_amdgcn_mfma_f32_32x32x16_bf16(a1, bb, acc01, 0, 0, 0);
            }
            {
                int iy = 4*rp + 2 + dy;
                const __bf16* bp = lin + (iy*IXN + dx)*CIP + bconst;
                bf16x4 l0 = *(const bf16x4*)bp;
                bf16x4 h0 = *(const bf16x4*)(bp + 4);
                bf16x8 bb = __builtin_shufflevector(l0, h0, 0,1,2,3,4,5,6,7);
                acc10 = __builtin_amdgcn_mfma_f32_32x32x16_bf16(a0, bb, acc10, 0, 0, 0);
                acc11 = __builtin_amdgcn_mfma_f32_32x32x16_bf16(a1, bb, acc11, 0, 0, 0);
            }
        }
    }

    int oxg = ct*32 + n;
    if (oxg < WO) {
        #pragma unroll
        for (int nt = 0; nt < 2; ++nt) {
            int oy = rg*4 + 2*rp + nt;
            if (oy >= HO) continue;
            #pragma unroll
            for (int mh = 0; mh < 2; ++mh) {
                const floatx16& acc = nt ? (mh ? acc11 : acc10) : (mh ? acc01 : acc00);
                #pragma unroll
                for (int reg = 0; reg < 16; ++reg) {
                    int cout = mh*32 + (reg & 3) + 8*(reg >> 2) + 4*h;
                    float val = acc[reg] + aggb[b*DIMC + cout];
                    out[(size_t)(b*DIMC + cout)*PIX + oy*WO + oxg] = val;
                }
            }
        }
    }
}

// ================= SMALL-WS fallback (R2 pipeline) =================

__global__ void pool_kernel(const float* __restrict__ x, float* __restrict__ pooled) {
    int plane = blockIdx.x >> 1, half = blockIdx.x & 1;
    const float4* p = (const float4*)(x + (size_t)plane * (HH*WW)) + half * 8192;
    float s = 0.f;
    for (int k = threadIdx.x; k < 8192; k += 256) {
        float4 v = p[k];
        s += (v.x + v.y) + (v.z + v.w);
    }
    for (int off = 32; off > 0; off >>= 1) s += __shfl_down(s, off, 64);
    __shared__ float red[4];
    if ((threadIdx.x & 63) == 0) red[threadIdx.x >> 6] = s;
    __syncthreads();
    if (threadIdx.x == 0) atomicAdd(&pooled[plane], red[0] + red[1] + red[2] + red[3]);
}

// conv staging directly from fp32 x (R2, known-good)
__global__ __launch_bounds__(256) void conv_small_kernel(const float* __restrict__ x,
                                                         const __bf16* __restrict__ a2,
                                                         const float* __restrict__ aggb,
                                                         float* __restrict__ out) {
    __shared__ __bf16 lin[11*IXN*CIP];
    int ct = blockIdx.x;
    int rg = blockIdx.y;
    int b  = blockIdx.z;
    int tid = threadIdx.x, lane = tid & 63, w = tid >> 6;
    int mh = w & 1;
    int rp = w >> 1;
    int n = lane & 31, h = lane >> 5;
    floatx16 acc0 = {}, acc1 = {};
    int gx0 = ct*64 - 1;
    int gy0 = rg*8 - 1;
    const float* xbse = x + (size_t)b * (DIMC*HH*WW);
    int bconst = 40*n + 8*h;

    for (int c = 0; c < 4; ++c) {
        __syncthreads();
        for (int rr = w; rr < 176; rr += 4) {
            int s = rr / 11, iy = rr - s*11;
            int gy = gy0 + iy;
            bool rowok = (unsigned)gy < (unsigned)HH;
            const float* row = xbse + (size_t)(c*16 + s)*(HH*WW) + gy*WW;
            int gx = gx0 + lane;
            float v0 = 0.f;
            if (rowok && (unsigned)gx < (unsigned)WW) v0 = row[gx];
            lin[(iy*IXN + lane)*CIP + s] = (__bf16)v0;
            int ix2 = lane + 64;
            if (ix2 < 67) {
                int gx2 = gx0 + ix2;
                float v1 = 0.f;
                if (rowok && (unsigned)gx2 < (unsigned)WW) v1 = row[gx2];
                lin[(iy*IXN + ix2)*CIP + s] = (__bf16)v1;
            }
        }
        __syncthreads();

        const __bf16* ap = a2 + ((size_t)(b*4 + c)*25*64 + (size_t)(mh*32 + n))*16 + h*8;
        #pragma unroll 5
        for (int t = 0; t < 25; ++t) {
            int dy = t / 5, dx = t - dy*5;
            bf16x8 a = *(const bf16x8*)(ap + t*1024);
            {
                int iy = 4*rp + dy;
                const __bf16* bp = lin + (iy*IXN + dx)*CIP + bconst;
                bf16x4 lo = *(const bf16x4*)bp;
                bf16x4 hi = *(const bf16x4*)(bp + 4);
                bf16x8 bb = __builtin_shufflevector(lo, hi, 0,1,2,3,4,5,6,7);
                acc0 = __builtin_amdgcn_mfma_f32_32x32x16_bf16(a, bb, acc0, 0, 0, 0);
            }
            {
                int iy = 4*rp + 2 + dy;
                const __bf16* bp = lin + (iy*IXN + dx)*CIP + bconst;
                bf16x4 lo = *(const bf16x4*)bp;
                bf16x4 hi = *(const bf16x4*)(bp + 4);
                bf16x8 bb = __builtin_shufflevector(lo, hi, 0,1,2,3,4,5,6,7);
                acc1 = __builtin_amdgcn_mfma_f32_32x32x16_bf16(a, bb, acc1, 0, 0, 0);
            }
        }
    }

    int oxg = ct*32 + n;
    if (oxg < WO) {
        #pragma unroll
        for (int nt = 0; nt < 2; ++nt) {
            int oy = rg*4 + 2*rp + nt;
            if (oy >= HO) continue;
            const floatx16& acc = nt ? acc1 : acc0;
            #pragma unroll
            for (int reg = 0; reg < 16; ++reg) {
                int row = (reg & 3) + 8*(reg >> 2) + 4*h;
                int cout = mh*32 + row;
                float val = acc[reg] + aggb[b*DIMC + cout];
                out[(size_t)(b*DIMC + cout)*PIX + oy*WO + oxg] = val;
            }
        }
    }
}

extern "C" void kernel_launch(void* const* d_in, const int* in_sizes, int n_in,
                              void* d_out, int out_size, void* d_ws, size_t ws_size,
                              hipStream_t stream) {
    const float* x      = (const float*)d_in[0];
    const float* fc1_w  = (const float*)d_in[1];
    const float* fc1_b  = (const float*)d_in[2];
    const float* fc2_w  = (const float*)d_in[3];
    const float* fc2_b  = (const float*)d_in[4];
    const float* weight = (const float*)d_in[5];
    const float* bias   = (const float*)d_in[6];
    float* out = (float*)d_out;
    float* ws  = (float*)d_ws;

    if (ws_size >= BG_NEED_BYTES) {
        __bf16* a2 = (__bf16*)(ws + BG_A2F);
        __bf16* xb = (__bf16*)(ws + BG_XB);
        hipMemsetAsync(ws + BG_POOLED, 0, 1024*sizeof(float), stream);
        pool_cvt_kernel<<<dim3(HH/PROWS, 4, BATCH), 256, 0, stream>>>(x, xb, ws + BG_POOLED);
        att_kernel<<<1, 256, 0, stream>>>(fc1_w, fc1_b, fc2_w, fc2_b, bias,
                                          ws + BG_POOLED, ws + BG_ATT, ws + BG_AGGB);
        agg_kernel<<<BATCH*DIMC*DIMC*25/256, 256, 0, stream>>>(weight, ws + BG_ATT,
                                                               a2, out + OUT_MAIN);
        conv_big_kernel<<<dim3(4, 32, BATCH), 128, 0, stream>>>(xb, a2, ws + BG_AGGB, out);
    } else {
        __bf16* a2 = (__bf16*)(ws + SM_A2F);
        hipMemsetAsync(ws + SM_POOLED, 0, 1024*sizeof(float), stream);
        pool_kernel<<<2*BATCH*DIMC, 256, 0, stream>>>(x, ws + SM_POOLED);
        att_kernel<<<1, 256, 0, stream>>>(fc1_w, fc1_b, fc2_w, fc2_b, bias,
                                          ws + SM_POOLED, ws + SM_ATT, ws + SM_AGGB);
        agg_kernel<<<BATCH*DIMC*DIMC*25/256, 256, 0, stream>>>(weight, ws + SM_ATT,
                                                               a2, out + OUT_MAIN);
        conv_small_kernel<<<dim3(4, 32, BATCH), 256, 0, stream>>>(x, a2, ws + SM_AGGB, out);
    }
}

// Round 4
// 536.185 us; speedup vs baseline: 1.0791x; 1.0523x over previous
//
#include <hip/hip_runtime.h>
#include <math.h>

#define DIMC 64
#define KK 4
#define BATCH 16
#define HH 256
#define WW 256
#define HO 127
#define WO 127
#define PIX (HO*WO)                  // 16129
#define OUT_MAIN (BATCH*DIMC*PIX)    // 16516096

typedef __bf16 bf16x4 __attribute__((ext_vector_type(4)));
typedef __bf16 bf16x8 __attribute__((ext_vector_type(8)));
typedef float floatx4 __attribute__((ext_vector_type(4)));
typedef float floatx16 __attribute__((ext_vector_type(16)));

// ---------- BIG-WS layout (float offsets) ----------
#define BG_A2F    0
#define BG_XB     819200
#define BG_POOLED (BG_XB + 33554432)          // 34,373,632
#define BG_ATT    (BG_POOLED + 1024)
#define BG_AGGB   (BG_ATT + 64)
#define BG_END    (BG_AGGB + 1024)            // 34,375,744 floats
#define BG_NEED_BYTES ((size_t)BG_END * 4)    // ~137.5 MB

// ---------- SMALL-WS (fallback, R2) layout ----------
#define SM_A2F    0
#define SM_POOLED 819200
#define SM_ATT    (SM_POOLED + 1024)
#define SM_AGGB   (SM_ATT + 64)

#define IXN 68
#define CIP 20

// rows per pool block
#define PROWS 8

// ================= shared kernels =================

// attention + agg_b (pooled holds raw sums; /65536 here)
__global__ void att_kernel(const float* __restrict__ fc1_w, const float* __restrict__ fc1_b,
                           const float* __restrict__ fc2_w, const float* __restrict__ fc2_b,
                           const float* __restrict__ bias,
                           const float* __restrict__ pooled_raw,
                           float* __restrict__ att_out, float* __restrict__ aggb_out) {
    __shared__ float sa[BATCH][KK];
    __shared__ float satt[BATCH*KK];
    int tid = threadIdx.x;
    {
        int b = tid >> 4, j = (tid >> 2) & 3, q = tid & 3;
        const float* pooled = pooled_raw + b*DIMC + q*16;
        const float* wrow   = fc1_w + j*DIMC + q*16;
        float s = 0.f;
        #pragma unroll
        for (int i = 0; i < 16; ++i) s += pooled[i] * (1.f/65536.f) * wrow[i];
        s += __shfl_xor(s, 1, 64);
        s += __shfl_xor(s, 2, 64);
        if (q == 0) sa[b][j] = fmaxf(s + fc1_b[j], 0.f);
    }
    __syncthreads();
    if (tid < BATCH) {
        int b = tid;
        float l[KK]; float m = -1e30f;
        #pragma unroll
        for (int j = 0; j < KK; ++j) {
            float s = fc2_b[j];
            #pragma unroll
            for (int k = 0; k < KK; ++k) s += sa[b][k] * fc2_w[j*KK + k];
            l[j] = s; m = fmaxf(m, s);
        }
        float e[KK]; float Z = 0.f;
        #pragma unroll
        for (int j = 0; j < KK; ++j) { e[j] = expf(l[j] - m); Z += e[j]; }
        float invZ = 1.f / Z;
        #pragma unroll
        for (int j = 0; j < KK; ++j) {
            float av = e[j] * invZ;
            satt[b*KK + j] = av;
            att_out[b*KK + j] = av;
        }
    }
    __syncthreads();
    for (int idx = tid; idx < BATCH*DIMC; idx += blockDim.x) {
        int b = idx / DIMC, o = idx % DIMC;
        float s = 0.f;
        #pragma unroll
        for (int k = 0; k < KK; ++k) s += satt[b*KK + k] * bias[k*DIMC + o];
        aggb_out[idx] = s;
    }
}

// mix weight bank -> w_ret (fp32) + a2 (bf16 MFMA-A layout)
__global__ void agg_kernel(const float* __restrict__ weight, const float* __restrict__ att,
                           __bf16* __restrict__ a2, float* __restrict__ wret) {
    int v = blockIdx.x * 256 + threadIdx.x;   // 0..1638399
    int i = v & 63;                            // ci
    int t = (v >> 6) % 25;                     // tap
    int o = (v / 1600) & 63;                   // cout
    int b = v / 102400;
    float s = 0.f;
    #pragma unroll
    for (int k = 0; k < KK; ++k)
        s += att[b*KK + k] * weight[((k*DIMC + o)*DIMC + i)*25 + t];
    wret[v] = s;
    a2[(((b*4 + (i >> 4))*25 + t)*64 + o)*16 + (i & 15)] = (__bf16)s;
}

// ================= BIG-WS fast path =================

// fused pool + fp32->bf16 swizzle: xb layout [b][chunk][y][x][ci16]
__global__ __launch_bounds__(256) void pool_cvt_kernel(const float* __restrict__ x,
                                                       __bf16* __restrict__ xb,
                                                       float* __restrict__ pooled) {
    int yg = blockIdx.x, ch = blockIdx.y, b = blockIdx.z;
    int tid = threadIdx.x, lane = tid & 63, w = tid >> 6;
    float acc[16];
    #pragma unroll
    for (int s = 0; s < 16; ++s) acc[s] = 0.f;
    #pragma unroll
    for (int ry = 0; ry < 2; ++ry) {
        int y = yg*PROWS + w*2 + ry;
        const float* src = x + (((size_t)(b*DIMC + ch*16))*HH + y)*WW + lane*4;
        floatx4 v[16];
        #pragma unroll
        for (int s = 0; s < 16; ++s) v[s] = *(const floatx4*)(src + (size_t)s*HH*WW);
        __bf16* dst = xb + ((((size_t)(b*4 + ch))*HH + y)*WW + lane*4)*16;
        #pragma unroll
        for (int p = 0; p < 4; ++p) {
            bf16x8 lo, hi;
            #pragma unroll
            for (int j = 0; j < 8; ++j) {
                lo[j] = (__bf16)v[j][p];
                hi[j] = (__bf16)v[j+8][p];
            }
            *(bf16x8*)(dst + p*16) = lo;
            *(bf16x8*)(dst + p*16 + 8) = hi;
        }
        #pragma unroll
        for (int s = 0; s < 16; ++s)
            acc[s] += (v[s][0] + v[s][1]) + (v[s][2] + v[s][3]);
    }
    #pragma unroll
    for (int s = 0; s < 16; ++s) {
        float t = acc[s];
        for (int off = 32; off > 0; off >>= 1) t += __shfl_down(t, off, 64);
        acc[s] = t;
    }
    __shared__ float part[4][16];
    if (lane == 0) {
        #pragma unroll
        for (int s = 0; s < 16; ++s) part[w][s] = acc[s];
    }
    __syncthreads();
    if (tid < 16) {
        float p = part[0][tid] + part[1][tid] + part[2][tid] + part[3][tid];
        atomicAdd(&pooled[b*DIMC + ch*16 + tid], p);
    }
}

// MFMA conv, staging from pre-converted bf16 xb.
// R3: 256 thr = 4 waves per block, (rp,mh) wave split (conv_small decomposition)
// -> ~16 waves/CU resident (was ~5), per-wave critical path halves.
// T14 prefetch retained: next chunk's 6x16B pieces/thread loaded into regs
// before the MFMA loop, ds_written after the next barrier.
__global__ __launch_bounds__(256) void conv_big_kernel(const __bf16* __restrict__ xb,
                                                       const __bf16* __restrict__ a2,
                                                       const float* __restrict__ aggb,
                                                       float* __restrict__ out) {
    __shared__ __bf16 lin[11*IXN*CIP];   // 29,920 B
    int ct = blockIdx.x;      // col tile 0..3
    int rg = blockIdx.y;      // row group 0..31
    int b  = blockIdx.z;
    int tid = threadIdx.x, lane = tid & 63, w = tid >> 6;
    int mh = w & 1;           // cout half
    int rp = w >> 1;          // row pair
    int n = lane & 31, h = lane >> 5;
    int gx0 = ct*64 - 1, gy0 = rg*8 - 1;
    int bconst = 40*n + 8*h;
    floatx16 acc0 = {}, acc1 = {};

    bf16x8 pre[6];
    // prologue: issue chunk-0 staging loads
    {
        const __bf16* xsrc = xb + ((size_t)(b*4 + 0))*HH*WW*16;
        #pragma unroll
        for (int it = 0; it < 6; ++it) {
            int idx = it*256 + tid;
            bf16x8 vv = {};
            if (idx < 1474) {
                int r = idx / 134;
                int q = idx - r*134;
                int ix = q >> 1, hh = q & 1;
                int gy = gy0 + r, gx = gx0 + ix;
                if ((unsigned)gy < (unsigned)HH && (unsigned)gx < (unsigned)WW)
                    vv = *(const bf16x8*)(xsrc + ((size_t)gy*WW + gx)*16 + hh*8);
            }
            pre[it] = vv;
        }
    }

    for (int c = 0; c < 4; ++c) {
        __syncthreads();                 // previous chunk's readers done
        // write prefetched pieces -> LDS
        #pragma unroll
        for (int it = 0; it < 6; ++it) {
            int idx = it*256 + tid;
            if (idx < 1474) {
                int r = idx / 134;
                int q = idx - r*134;
                int ix = q >> 1, hh = q & 1;
                __bf16* dp = lin + (r*IXN + ix)*CIP + hh*8;
                bf16x4 vlo = {pre[it][0], pre[it][1], pre[it][2], pre[it][3]};
                bf16x4 vhi = {pre[it][4], pre[it][5], pre[it][6], pre[it][7]};
                *(bf16x4*)dp = vlo;
                *(bf16x4*)(dp + 4) = vhi;
            }
        }
        __syncthreads();
        // issue next chunk's loads now; consumed after the next barrier
        if (c < 3) {
            const __bf16* xsrc = xb + ((size_t)(b*4 + c + 1))*HH*WW*16;
            #pragma unroll
            for (int it = 0; it < 6; ++it) {
                int idx = it*256 + tid;
                bf16x8 vv = {};
                if (idx < 1474) {
                    int r = idx / 134;
                    int q = idx - r*134;
                    int ix = q >> 1, hh = q & 1;
                    int gy = gy0 + r, gx = gx0 + ix;
                    if ((unsigned)gy < (unsigned)HH && (unsigned)gx < (unsigned)WW)
                        vv = *(const bf16x8*)(xsrc + ((size_t)gy*WW + gx)*16 + hh*8);
                }
                pre[it] = vv;
            }
        }

        const __bf16* ap = a2 + ((size_t)(b*4 + c)*25*64 + (size_t)(mh*32 + n))*16 + h*8;
        #pragma unroll 5
        for (int t = 0; t < 25; ++t) {
            int dy = t / 5, dx = t - dy*5;
            bf16x8 a = *(const bf16x8*)(ap + t*1024);
            {
                int iy = 4*rp + dy;
                const __bf16* bp = lin + (iy*IXN + dx)*CIP + bconst;
                bf16x4 l0 = *(const bf16x4*)bp;
                bf16x4 h0 = *(const bf16x4*)(bp + 4);
                bf16x8 bb = __builtin_shufflevector(l0, h0, 0,1,2,3,4,5,6,7);
                acc0 = __builtin_amdgcn_mfma_f32_32x32x16_bf16(a, bb, acc0, 0, 0, 0);
            }
            {
                int iy = 4*rp + 2 + dy;
                const __bf16* bp = lin + (iy*IXN + dx)*CIP + bconst;
                bf16x4 l0 = *(const bf16x4*)bp;
                bf16x4 h0 = *(const bf16x4*)(bp + 4);
                bf16x8 bb = __builtin_shufflevector(l0, h0, 0,1,2,3,4,5,6,7);
                acc1 = __builtin_amdgcn_mfma_f32_32x32x16_bf16(a, bb, acc1, 0, 0, 0);
            }
        }
    }

    int oxg = ct*32 + n;
    if (oxg < WO) {
        #pragma unroll
        for (int nt = 0; nt < 2; ++nt) {
            int oy = rg*4 + 2*rp + nt;
            if (oy >= HO) continue;
            const floatx16& acc = nt ? acc1 : acc0;
            #pragma unroll
            for (int reg = 0; reg < 16; ++reg) {
                int row = (reg & 3) + 8*(reg >> 2) + 4*h;
                int cout = mh*32 + row;
                float val = acc[reg] + aggb[b*DIMC + cout];
                out[(size_t)(b*DIMC + cout)*PIX + oy*WO + oxg] = val;
            }
        }
    }
}

// ================= SMALL-WS fallback (R2 pipeline) =================

__global__ void pool_kernel(const float* __restrict__ x, float* __restrict__ pooled) {
    int plane = blockIdx.x >> 1, half = blockIdx.x & 1;
    const float4* p = (const float4*)(x + (size_t)plane * (HH*WW)) + half * 8192;
    float s = 0.f;
    for (int k = threadIdx.x; k < 8192; k += 256) {
        float4 v = p[k];
        s += (v.x + v.y) + (v.z + v.w);
    }
    for (int off = 32; off > 0; off >>= 1) s += __shfl_down(s, off, 64);
    __shared__ float red[4];
    if ((threadIdx.x & 63) == 0) red[threadIdx.x >> 6] = s;
    __syncthreads();
    if (threadIdx.x == 0) atomicAdd(&pooled[plane], red[0] + red[1] + red[2] + red[3]);
}

// conv staging directly from fp32 x (R2, known-good)
__global__ __launch_bounds__(256) void conv_small_kernel(const float* __restrict__ x,
                                                         const __bf16* __restrict__ a2,
                                                         const float* __restrict__ aggb,
                                                         float* __restrict__ out) {
    __shared__ __bf16 lin[11*IXN*CIP];
    int ct = blockIdx.x;
    int rg = blockIdx.y;
    int b  = blockIdx.z;
    int tid = threadIdx.x, lane = tid & 63, w = tid >> 6;
    int mh = w & 1;
    int rp = w >> 1;
    int n = lane & 31, h = lane >> 5;
    floatx16 acc0 = {}, acc1 = {};
    int gx0 = ct*64 - 1;
    int gy0 = rg*8 - 1;
    const float* xbse = x + (size_t)b * (DIMC*HH*WW);
    int bconst = 40*n + 8*h;

    for (int c = 0; c < 4; ++c) {
        __syncthreads();
        for (int rr = w; rr < 176; rr += 4) {
            int s = rr / 11, iy = rr - s*11;
            int gy = gy0 + iy;
            bool rowok = (unsigned)gy < (unsigned)HH;
            const float* row = xbse + (size_t)(c*16 + s)*(HH*WW) + gy*WW;
            int gx = gx0 + lane;
            float v0 = 0.f;
            if (rowok && (unsigned)gx < (unsigned)WW) v0 = row[gx];
            lin[(iy*IXN + lane)*CIP + s] = (__bf16)v0;
            int ix2 = lane + 64;
            if (ix2 < 67) {
                int gx2 = gx0 + ix2;
                float v1 = 0.f;
                if (rowok && (unsigned)gx2 < (unsigned)WW) v1 = row[gx2];
                lin[(iy*IXN + ix2)*CIP + s] = (__bf16)v1;
            }
        }
        __syncthreads();

        const __bf16* ap = a2 + ((size_t)(b*4 + c)*25*64 + (size_t)(mh*32 + n))*16 + h*8;
        #pragma unroll 5
        for (int t = 0; t < 25; ++t) {
            int dy = t / 5, dx = t - dy*5;
            bf16x8 a = *(const bf16x8*)(ap + t*1024);
            {
                int iy = 4*rp + dy;
                const __bf16* bp = lin + (iy*IXN + dx)*CIP + bconst;
                bf16x4 lo = *(const bf16x4*)bp;
                bf16x4 hi = *(const bf16x4*)(bp + 4);
                bf16x8 bb = __builtin_shufflevector(lo, hi, 0,1,2,3,4,5,6,7);
                acc0 = __builtin_amdgcn_mfma_f32_32x32x16_bf16(a, bb, acc0, 0, 0, 0);
            }
            {
                int iy = 4*rp + 2 + dy;
                const __bf16* bp = lin + (iy*IXN + dx)*CIP + bconst;
                bf16x4 lo = *(const bf16x4*)bp;
                bf16x4 hi = *(const bf16x4*)(bp + 4);
                bf16x8 bb = __builtin_shufflevector(lo, hi, 0,1,2,3,4,5,6,7);
                acc1 = __builtin_amdgcn_mfma_f32_32x32x16_bf16(a, bb, acc1, 0, 0, 0);
            }
        }
    }

    int oxg = ct*32 + n;
    if (oxg < WO) {
        #pragma unroll
        for (int nt = 0; nt < 2; ++nt) {
            int oy = rg*4 + 2*rp + nt;
            if (oy >= HO) continue;
            const floatx16& acc = nt ? acc1 : acc0;
            #pragma unroll
            for (int reg = 0; reg < 16; ++reg) {
                int row = (reg & 3) + 8*(reg >> 2) + 4*h;
                int cout = mh*32 + row;
                float val = acc[reg] + aggb[b*DIMC + cout];
                out[(size_t)(b*DIMC + cout)*PIX + oy*WO + oxg] = val;
            }
        }
    }
}

extern "C" void kernel_launch(void* const* d_in, const int* in_sizes, int n_in,
                              void* d_out, int out_size, void* d_ws, size_t ws_size,
                              hipStream_t stream) {
    const float* x      = (const float*)d_in[0];
    const float* fc1_w  = (const float*)d_in[1];
    const float* fc1_b  = (const float*)d_in[2];
    const float* fc2_w  = (const float*)d_in[3];
    const float* fc2_b  = (const float*)d_in[4];
    const float* weight = (const float*)d_in[5];
    const float* bias   = (const float*)d_in[6];
    float* out = (float*)d_out;
    float* ws  = (float*)d_ws;

    if (ws_size >= BG_NEED_BYTES) {
        __bf16* a2 = (__bf16*)(ws + BG_A2F);
        __bf16* xb = (__bf16*)(ws + BG_XB);
        hipMemsetAsync(ws + BG_POOLED, 0, 1024*sizeof(float), stream);
        pool_cvt_kernel<<<dim3(HH/PROWS, 4, BATCH), 256, 0, stream>>>(x, xb, ws + BG_POOLED);
        att_kernel<<<1, 256, 0, stream>>>(fc1_w, fc1_b, fc2_w, fc2_b, bias,
                                          ws + BG_POOLED, ws + BG_ATT, ws + BG_AGGB);
        agg_kernel<<<BATCH*DIMC*DIMC*25/256, 256, 0, stream>>>(weight, ws + BG_ATT,
                                                               a2, out + OUT_MAIN);
        conv_big_kernel<<<dim3(4, 32, BATCH), 256, 0, stream>>>(xb, a2, ws + BG_AGGB, out);
    } else {
        __bf16* a2 = (__bf16*)(ws + SM_A2F);
        hipMemsetAsync(ws + SM_POOLED, 0, 1024*sizeof(float), stream);
        pool_kernel<<<2*BATCH*DIMC, 256, 0, stream>>>(x, ws + SM_POOLED);
        att_kernel<<<1, 256, 0, stream>>>(fc1_w, fc1_b, fc2_w, fc2_b, bias,
                                          ws + SM_POOLED, ws + SM_ATT, ws + SM_AGGB);
        agg_kernel<<<BATCH*DIMC*DIMC*25/256, 256, 0, stream>>>(weight, ws + SM_ATT,
                                                               a2, out + OUT_MAIN);
        conv_small_kernel<<<dim3(4, 32, BATCH), 256, 0, stream>>>(x, a2, ws + SM_AGGB, out);
    }
}

// Round 5
// 508.836 us; speedup vs baseline: 1.1371x; 1.0537x over previous
//
#include <hip/hip_runtime.h>
#include <math.h>

#define DIMC 64
#define KK 4
#define BATCH 16
#define HH 256
#define WW 256
#define HO 127
#define WO 127
#define PIX (HO*WO)                  // 16129
#define OUT_MAIN (BATCH*DIMC*PIX)    // 16516096

typedef __bf16 bf16x4 __attribute__((ext_vector_type(4)));
typedef __bf16 bf16x8 __attribute__((ext_vector_type(8)));
typedef float floatx4 __attribute__((ext_vector_type(4)));
typedef float floatx16 __attribute__((ext_vector_type(16)));

// ---------- BIG-WS layout (float offsets) ----------
#define BG_A2F    0
#define BG_XB     819200
#define BG_POOLED (BG_XB + 33554432)          // 34,373,632
#define BG_ATT    (BG_POOLED + 1024)
#define BG_AGGB   (BG_ATT + 64)
#define BG_END    (BG_AGGB + 1024)            // 34,375,744 floats
#define BG_NEED_BYTES ((size_t)BG_END * 4)    // ~137.5 MB

// ---------- SMALL-WS (fallback, R2) layout ----------
#define SM_A2F    0
#define SM_POOLED 819200
#define SM_ATT    (SM_POOLED + 1024)
#define SM_AGGB   (SM_ATT + 64)

#define IXN 68
#define CIP 20

// rows per pool block
#define PROWS 8

// ================= shared kernels =================

// attention + agg_b (pooled holds raw sums; /65536 here)
__global__ void att_kernel(const float* __restrict__ fc1_w, const float* __restrict__ fc1_b,
                           const float* __restrict__ fc2_w, const float* __restrict__ fc2_b,
                           const float* __restrict__ bias,
                           const float* __restrict__ pooled_raw,
                           float* __restrict__ att_out, float* __restrict__ aggb_out) {
    __shared__ float sa[BATCH][KK];
    __shared__ float satt[BATCH*KK];
    int tid = threadIdx.x;
    {
        int b = tid >> 4, j = (tid >> 2) & 3, q = tid & 3;
        const float* pooled = pooled_raw + b*DIMC + q*16;
        const float* wrow   = fc1_w + j*DIMC + q*16;
        float s = 0.f;
        #pragma unroll
        for (int i = 0; i < 16; ++i) s += pooled[i] * (1.f/65536.f) * wrow[i];
        s += __shfl_xor(s, 1, 64);
        s += __shfl_xor(s, 2, 64);
        if (q == 0) sa[b][j] = fmaxf(s + fc1_b[j], 0.f);
    }
    __syncthreads();
    if (tid < BATCH) {
        int b = tid;
        float l[KK]; float m = -1e30f;
        #pragma unroll
        for (int j = 0; j < KK; ++j) {
            float s = fc2_b[j];
            #pragma unroll
            for (int k = 0; k < KK; ++k) s += sa[b][k] * fc2_w[j*KK + k];
            l[j] = s; m = fmaxf(m, s);
        }
        float e[KK]; float Z = 0.f;
        #pragma unroll
        for (int j = 0; j < KK; ++j) { e[j] = expf(l[j] - m); Z += e[j]; }
        float invZ = 1.f / Z;
        #pragma unroll
        for (int j = 0; j < KK; ++j) {
            float av = e[j] * invZ;
            satt[b*KK + j] = av;
            att_out[b*KK + j] = av;
        }
    }
    __syncthreads();
    for (int idx = tid; idx < BATCH*DIMC; idx += blockDim.x) {
        int b = idx / DIMC, o = idx % DIMC;
        float s = 0.f;
        #pragma unroll
        for (int k = 0; k < KK; ++k) s += satt[b*KK + k] * bias[k*DIMC + o];
        aggb_out[idx] = s;
    }
}

// mix weight bank -> w_ret (fp32) + a2 (bf16 MFMA-A layout)
__global__ void agg_kernel(const float* __restrict__ weight, const float* __restrict__ att,
                           __bf16* __restrict__ a2, float* __restrict__ wret) {
    int v = blockIdx.x * 256 + threadIdx.x;   // 0..1638399
    int i = v & 63;                            // ci
    int t = (v >> 6) % 25;                     // tap
    int o = (v / 1600) & 63;                   // cout
    int b = v / 102400;
    float s = 0.f;
    #pragma unroll
    for (int k = 0; k < KK; ++k)
        s += att[b*KK + k] * weight[((k*DIMC + o)*DIMC + i)*25 + t];
    wret[v] = s;
    a2[(((b*4 + (i >> 4))*25 + t)*64 + o)*16 + (i & 15)] = (__bf16)s;
}

// ================= BIG-WS fast path =================

// fused pool + fp32->bf16 swizzle: xb layout [b][chunk][y][x][ci16]
__global__ __launch_bounds__(256) void pool_cvt_kernel(const float* __restrict__ x,
                                                       __bf16* __restrict__ xb,
                                                       float* __restrict__ pooled) {
    int yg = blockIdx.x, ch = blockIdx.y, b = blockIdx.z;
    int tid = threadIdx.x, lane = tid & 63, w = tid >> 6;
    float acc[16];
    #pragma unroll
    for (int s = 0; s < 16; ++s) acc[s] = 0.f;
    #pragma unroll
    for (int ry = 0; ry < 2; ++ry) {
        int y = yg*PROWS + w*2 + ry;
        const float* src = x + (((size_t)(b*DIMC + ch*16))*HH + y)*WW + lane*4;
        floatx4 v[16];
        #pragma unroll
        for (int s = 0; s < 16; ++s) v[s] = *(const floatx4*)(src + (size_t)s*HH*WW);
        __bf16* dst = xb + ((((size_t)(b*4 + ch))*HH + y)*WW + lane*4)*16;
        #pragma unroll
        for (int p = 0; p < 4; ++p) {
            bf16x8 lo, hi;
            #pragma unroll
            for (int j = 0; j < 8; ++j) {
                lo[j] = (__bf16)v[j][p];
                hi[j] = (__bf16)v[j+8][p];
            }
            *(bf16x8*)(dst + p*16) = lo;
            *(bf16x8*)(dst + p*16 + 8) = hi;
        }
        #pragma unroll
        for (int s = 0; s < 16; ++s)
            acc[s] += (v[s][0] + v[s][1]) + (v[s][2] + v[s][3]);
    }
    #pragma unroll
    for (int s = 0; s < 16; ++s) {
        float t = acc[s];
        for (int off = 32; off > 0; off >>= 1) t += __shfl_down(t, off, 64);
        acc[s] = t;
    }
    __shared__ float part[4][16];
    if (lane == 0) {
        #pragma unroll
        for (int s = 0; s < 16; ++s) part[w][s] = acc[s];
    }
    __syncthreads();
    if (tid < 16) {
        float p = part[0][tid] + part[1][tid] + part[2][tid] + part[3][tid];
        atomicAdd(&pooled[b*DIMC + ch*16 + tid], p);
    }
}

// MFMA conv, staging from pre-converted bf16 xb.
// R4: per-chunk a2 A-fragments fully preloaded into registers (pa[25], 100 VGPR).
// All 25 loads issue back-to-back (one latency exposure, hidden under the next
// barrier+ds_write phase for chunks 1..3) -> tap loop has ZERO global ops on the
// critical path. R3's 4-wave (rp,mh) split and T14 xb prefetch retained.
__global__ __launch_bounds__(256) void conv_big_kernel(const __bf16* __restrict__ xb,
                                                       const __bf16* __restrict__ a2,
                                                       const float* __restrict__ aggb,
                                                       float* __restrict__ out) {
    __shared__ __bf16 lin[11*IXN*CIP];   // 29,920 B
    int ct = blockIdx.x;      // col tile 0..3
    int rg = blockIdx.y;      // row group 0..31
    int b  = blockIdx.z;
    int tid = threadIdx.x, lane = tid & 63, w = tid >> 6;
    int mh = w & 1;           // cout half
    int rp = w >> 1;          // row pair
    int n = lane & 31, h = lane >> 5;
    int gx0 = ct*64 - 1, gy0 = rg*8 - 1;
    int bconst = 40*n + 8*h;
    floatx16 acc0 = {}, acc1 = {};

    bf16x8 pre[6];
    bf16x8 pa[25];
    // prologue: issue chunk-0 xb staging loads + chunk-0 a2 fragment loads
    {
        const __bf16* xsrc = xb + ((size_t)(b*4 + 0))*HH*WW*16;
        #pragma unroll
        for (int it = 0; it < 6; ++it) {
            int idx = it*256 + tid;
            bf16x8 vv = {};
            if (idx < 1474) {
                int r = idx / 134;
                int q = idx - r*134;
                int ix = q >> 1, hh = q & 1;
                int gy = gy0 + r, gx = gx0 + ix;
                if ((unsigned)gy < (unsigned)HH && (unsigned)gx < (unsigned)WW)
                    vv = *(const bf16x8*)(xsrc + ((size_t)gy*WW + gx)*16 + hh*8);
            }
            pre[it] = vv;
        }
        const __bf16* ap = a2 + ((size_t)(b*4 + 0)*25*64 + (size_t)(mh*32 + n))*16 + h*8;
        #pragma unroll
        for (int t = 0; t < 25; ++t) pa[t] = *(const bf16x8*)(ap + t*1024);
    }

    for (int c = 0; c < 4; ++c) {
        __syncthreads();                 // previous chunk's readers done
        // write prefetched xb pieces -> LDS
        #pragma unroll
        for (int it = 0; it < 6; ++it) {
            int idx = it*256 + tid;
            if (idx < 1474) {
                int r = idx / 134;
                int q = idx - r*134;
                int ix = q >> 1, hh = q & 1;
                __bf16* dp = lin + (r*IXN + ix)*CIP + hh*8;
                bf16x4 vlo = {pre[it][0], pre[it][1], pre[it][2], pre[it][3]};
                bf16x4 vhi = {pre[it][4], pre[it][5], pre[it][6], pre[it][7]};
                *(bf16x4*)dp = vlo;
                *(bf16x4*)(dp + 4) = vhi;
            }
        }
        __syncthreads();
        // issue next chunk's xb loads now; consumed after the next barrier
        if (c < 3) {
            const __bf16* xsrc = xb + ((size_t)(b*4 + c + 1))*HH*WW*16;
            #pragma unroll
            for (int it = 0; it < 6; ++it) {
                int idx = it*256 + tid;
                bf16x8 vv = {};
                if (idx < 1474) {
                    int r = idx / 134;
                    int q = idx - r*134;
                    int ix = q >> 1, hh = q & 1;
                    int gy = gy0 + r, gx = gx0 + ix;
                    if ((unsigned)gy < (unsigned)HH && (unsigned)gx < (unsigned)WW)
                        vv = *(const bf16x8*)(xsrc + ((size_t)gy*WW + gx)*16 + hh*8);
                }
                pre[it] = vv;
            }
        }

        // tap loop: pure reg-A x LDS-B -> MFMA (no global loads inside)
        #pragma unroll
        for (int t = 0; t < 25; ++t) {
            int dy = t / 5, dx = t - dy*5;
            bf16x8 a = pa[t];
            {
                int iy = 4*rp + dy;
                const __bf16* bp = lin + (iy*IXN + dx)*CIP + bconst;
                bf16x4 l0 = *(const bf16x4*)bp;
                bf16x4 h0 = *(const bf16x4*)(bp + 4);
                bf16x8 bb = __builtin_shufflevector(l0, h0, 0,1,2,3,4,5,6,7);
                acc0 = __builtin_amdgcn_mfma_f32_32x32x16_bf16(a, bb, acc0, 0, 0, 0);
            }
            {
                int iy = 4*rp + 2 + dy;
                const __bf16* bp = lin + (iy*IXN + dx)*CIP + bconst;
                bf16x4 l0 = *(const bf16x4*)bp;
                bf16x4 h0 = *(const bf16x4*)(bp + 4);
                bf16x8 bb = __builtin_shufflevector(l0, h0, 0,1,2,3,4,5,6,7);
                acc1 = __builtin_amdgcn_mfma_f32_32x32x16_bf16(a, bb, acc1, 0, 0, 0);
            }
        }

        // issue next chunk's a2 loads; latency hides under next barrier+ds_write
        if (c < 3) {
            const __bf16* ap = a2 + ((size_t)(b*4 + c + 1)*25*64 + (size_t)(mh*32 + n))*16 + h*8;
            #pragma unroll
            for (int t = 0; t < 25; ++t) pa[t] = *(const bf16x8*)(ap + t*1024);
        }
    }

    int oxg = ct*32 + n;
    if (oxg < WO) {
        #pragma unroll
        for (int nt = 0; nt < 2; ++nt) {
            int oy = rg*4 + 2*rp + nt;
            if (oy >= HO) continue;
            const floatx16& acc = nt ? acc1 : acc0;
            #pragma unroll
            for (int reg = 0; reg < 16; ++reg) {
                int row = (reg & 3) + 8*(reg >> 2) + 4*h;
                int cout = mh*32 + row;
                float val = acc[reg] + aggb[b*DIMC + cout];
                out[(size_t)(b*DIMC + cout)*PIX + oy*WO + oxg] = val;
            }
        }
    }
}

// ================= SMALL-WS fallback (R2 pipeline) =================

__global__ void pool_kernel(const float* __restrict__ x, float* __restrict__ pooled) {
    int plane = blockIdx.x >> 1, half = blockIdx.x & 1;
    const float4* p = (const float4*)(x + (size_t)plane * (HH*WW)) + half * 8192;
    float s = 0.f;
    for (int k = threadIdx.x; k < 8192; k += 256) {
        float4 v = p[k];
        s += (v.x + v.y) + (v.z + v.w);
    }
    for (int off = 32; off > 0; off >>= 1) s += __shfl_down(s, off, 64);
    __shared__ float red[4];
    if ((threadIdx.x & 63) == 0) red[threadIdx.x >> 6] = s;
    __syncthreads();
    if (threadIdx.x == 0) atomicAdd(&pooled[plane], red[0] + red[1] + red[2] + red[3]);
}

// conv staging directly from fp32 x (R2, known-good)
__global__ __launch_bounds__(256) void conv_small_kernel(const float* __restrict__ x,
                                                         const __bf16* __restrict__ a2,
                                                         const float* __restrict__ aggb,
                                                         float* __restrict__ out) {
    __shared__ __bf16 lin[11*IXN*CIP];
    int ct = blockIdx.x;
    int rg = blockIdx.y;
    int b  = blockIdx.z;
    int tid = threadIdx.x, lane = tid & 63, w = tid >> 6;
    int mh = w & 1;
    int rp = w >> 1;
    int n = lane & 31, h = lane >> 5;
    floatx16 acc0 = {}, acc1 = {};
    int gx0 = ct*64 - 1;
    int gy0 = rg*8 - 1;
    const float* xbse = x + (size_t)b * (DIMC*HH*WW);
    int bconst = 40*n + 8*h;

    for (int c = 0; c < 4; ++c) {
        __syncthreads();
        for (int rr = w; rr < 176; rr += 4) {
            int s = rr / 11, iy = rr - s*11;
            int gy = gy0 + iy;
            bool rowok = (unsigned)gy < (unsigned)HH;
            const float* row = xbse + (size_t)(c*16 + s)*(HH*WW) + gy*WW;
            int gx = gx0 + lane;
            float v0 = 0.f;
            if (rowok && (unsigned)gx < (unsigned)WW) v0 = row[gx];
            lin[(iy*IXN + lane)*CIP + s] = (__bf16)v0;
            int ix2 = lane + 64;
            if (ix2 < 67) {
                int gx2 = gx0 + ix2;
                float v1 = 0.f;
                if (rowok && (unsigned)gx2 < (unsigned)WW) v1 = row[gx2];
                lin[(iy*IXN + ix2)*CIP + s] = (__bf16)v1;
            }
        }
        __syncthreads();

        const __bf16* ap = a2 + ((size_t)(b*4 + c)*25*64 + (size_t)(mh*32 + n))*16 + h*8;
        #pragma unroll 5
        for (int t = 0; t < 25; ++t) {
            int dy = t / 5, dx = t - dy*5;
            bf16x8 a = *(const bf16x8*)(ap + t*1024);
            {
                int iy = 4*rp + dy;
                const __bf16* bp = lin + (iy*IXN + dx)*CIP + bconst;
                bf16x4 lo = *(const bf16x4*)bp;
                bf16x4 hi = *(const bf16x4*)(bp + 4);
                bf16x8 bb = __builtin_shufflevector(lo, hi, 0,1,2,3,4,5,6,7);
                acc0 = __builtin_amdgcn_mfma_f32_32x32x16_bf16(a, bb, acc0, 0, 0, 0);
            }
            {
                int iy = 4*rp + 2 + dy;
                const __bf16* bp = lin + (iy*IXN + dx)*CIP + bconst;
                bf16x4 lo = *(const bf16x4*)bp;
                bf16x4 hi = *(const bf16x4*)(bp + 4);
                bf16x8 bb = __builtin_shufflevector(lo, hi, 0,1,2,3,4,5,6,7);
                acc1 = __builtin_amdgcn_mfma_f32_32x32x16_bf16(a, bb, acc1, 0, 0, 0);
            }
        }
    }

    int oxg = ct*32 + n;
    if (oxg < WO) {
        #pragma unroll
        for (int nt = 0; nt < 2; ++nt) {
            int oy = rg*4 + 2*rp + nt;
            if (oy >= HO) continue;
            const floatx16& acc = nt ? acc1 : acc0;
            #pragma unroll
            for (int reg = 0; reg < 16; ++reg) {
                int row = (reg & 3) + 8*(reg >> 2) + 4*h;
                int cout = mh*32 + row;
                float val = acc[reg] + aggb[b*DIMC + cout];
                out[(size_t)(b*DIMC + cout)*PIX + oy*WO + oxg] = val;
            }
        }
    }
}

extern "C" void kernel_launch(void* const* d_in, const int* in_sizes, int n_in,
                              void* d_out, int out_size, void* d_ws, size_t ws_size,
                              hipStream_t stream) {
    const float* x      = (const float*)d_in[0];
    const float* fc1_w  = (const float*)d_in[1];
    const float* fc1_b  = (const float*)d_in[2];
    const float* fc2_w  = (const float*)d_in[3];
    const float* fc2_b  = (const float*)d_in[4];
    const float* weight = (const float*)d_in[5];
    const float* bias   = (const float*)d_in[6];
    float* out = (float*)d_out;
    float* ws  = (float*)d_ws;

    if (ws_size >= BG_NEED_BYTES) {
        __bf16* a2 = (__bf16*)(ws + BG_A2F);
        __bf16* xb = (__bf16*)(ws + BG_XB);
        hipMemsetAsync(ws + BG_POOLED, 0, 1024*sizeof(float), stream);
        pool_cvt_kernel<<<dim3(HH/PROWS, 4, BATCH), 256, 0, stream>>>(x, xb, ws + BG_POOLED);
        att_kernel<<<1, 256, 0, stream>>>(fc1_w, fc1_b, fc2_w, fc2_b, bias,
                                          ws + BG_POOLED, ws + BG_ATT, ws + BG_AGGB);
        agg_kernel<<<BATCH*DIMC*DIMC*25/256, 256, 0, stream>>>(weight, ws + BG_ATT,
                                                               a2, out + OUT_MAIN);
        conv_big_kernel<<<dim3(4, 32, BATCH), 256, 0, stream>>>(xb, a2, ws + BG_AGGB, out);
    } else {
        __bf16* a2 = (__bf16*)(ws + SM_A2F);
        hipMemsetAsync(ws + SM_POOLED, 0, 1024*sizeof(float), stream);
        pool_kernel<<<2*BATCH*DIMC, 256, 0, stream>>>(x, ws + SM_POOLED);
        att_kernel<<<1, 256, 0, stream>>>(fc1_w, fc1_b, fc2_w, fc2_b, bias,
                                          ws + SM_POOLED, ws + SM_ATT, ws + SM_AGGB);
        agg_kernel<<<BATCH*DIMC*DIMC*25/256, 256, 0, stream>>>(weight, ws + SM_ATT,
                                                               a2, out + OUT_MAIN);
        conv_small_kernel<<<dim3(4, 32, BATCH), 256, 0, stream>>>(x, a2, ws + SM_AGGB, out);
    }
}